// Round 2
// baseline (9024.963 us; speedup 1.0000x reference)
//
#include <hip/hip_runtime.h>
#include <hip/hip_bf16.h>
#include <math.h>

#define T_STEPS 512
#define BATCH   128
#define ISZ     256
#define HSZ     256
#define G4      1024   // 4*H

// ---------------------------------------------------------------------------
// prep: build transposed weight tables WT4[k4][row][c] = W[row][4*k4+c]
// so that per-k4 weight loads are coalesced float4s across rows.
// ---------------------------------------------------------------------------
__global__ __launch_bounds__(256) void prep_tables(
    const float* __restrict__ W_hh, const float* __restrict__ W_ih,
    float* __restrict__ WT4h, float* __restrict__ WT4i) {
  int idx = blockIdx.x * 256 + threadIdx.x;   // 0 .. 262143
  int k4 = idx >> 12;          // 0..63   (4096 = 1024 rows * 4)
  int r  = (idx >> 2) & 1023;  // row
  int c  = idx & 3;
  WT4h[idx] = W_hh[r * 256 + k4 * 4 + c];
  WT4i[idx] = W_ih[r * 256 + k4 * 4 + c];
}

// ---------------------------------------------------------------------------
// Phase 1: G[m, j] = sum_k X[m,k] * W_ih[j,k] + b_ih[j] + b_hh[j]
// M = T*B = 65536, N = 1024, K = 256.
// 128x128 tile, 8x8 micro-tile (2 FLOP per LDS byte -> VALU-bound),
// XOR-swizzled LDS (slot ^= (row>>2)&7) for conflict-free fp32 b128 reads.
// ---------------------------------------------------------------------------
#define BK 32
__global__ __launch_bounds__(256, 2) void gemm_gates(
    const float* __restrict__ X,    // [65536, 256]
    const float* __restrict__ Wih,  // [1024, 256]
    const float* __restrict__ bih, const float* __restrict__ bhh,
    float* __restrict__ G) {        // [65536, 1024]
  __shared__ __align__(16) float As[128][32];
  __shared__ __align__(16) float Bs[128][32];
  const int m0 = blockIdx.y * 128;
  const int j0 = blockIdx.x * 128;
  const int t  = threadIdx.x;
  const int tx = t & 15;   // col group: cols j0 + tx*8 .. +7
  const int ty = t >> 4;   // row group: rows m0 + ty*8 .. +7
  float acc[8][8] = {};
  for (int k0 = 0; k0 < 256; k0 += BK) {
    #pragma unroll
    for (int i = 0; i < 4; ++i) {
      int f = t + i * 256;               // 0..1023 float4 stage slots
      int row = f >> 3, kq = f & 7;
      int sa = (kq ^ ((row >> 2) & 7)) * 4;   // swizzled float4 slot
      float4 va = *reinterpret_cast<const float4*>(&X[(size_t)(m0 + row) * 256 + k0 + kq * 4]);
      float4 vb = *reinterpret_cast<const float4*>(&Wih[(size_t)(j0 + row) * 256 + k0 + kq * 4]);
      *reinterpret_cast<float4*>(&As[row][sa]) = va;
      *reinterpret_cast<float4*>(&Bs[row][sa]) = vb;
    }
    __syncthreads();
    #pragma unroll
    for (int kk4 = 0; kk4 < BK / 4; ++kk4) {
      float4 a[8], b[8];
      #pragma unroll
      for (int i = 0; i < 8; ++i) {
        int row = ty * 8 + i;
        a[i] = *reinterpret_cast<const float4*>(&As[row][(kk4 ^ ((row >> 2) & 7)) * 4]);
      }
      #pragma unroll
      for (int j = 0; j < 8; ++j) {
        int row = tx * 8 + j;
        b[j] = *reinterpret_cast<const float4*>(&Bs[row][(kk4 ^ ((row >> 2) & 7)) * 4]);
      }
      #pragma unroll
      for (int i = 0; i < 8; ++i)
        #pragma unroll
        for (int j = 0; j < 8; ++j)
          acc[i][j] += a[i].x * b[j].x + a[i].y * b[j].y + a[i].z * b[j].z + a[i].w * b[j].w;
    }
    __syncthreads();
  }
  // epilogue: + (b_ih + b_hh), store two float4s per row
  float4 bv[2];
  #pragma unroll
  for (int q = 0; q < 2; ++q) {
    float4 u0 = *reinterpret_cast<const float4*>(&bih[j0 + tx * 8 + q * 4]);
    float4 u1 = *reinterpret_cast<const float4*>(&bhh[j0 + tx * 8 + q * 4]);
    bv[q] = make_float4(u0.x + u1.x, u0.y + u1.y, u0.z + u1.z, u0.w + u1.w);
  }
  #pragma unroll
  for (int i = 0; i < 8; ++i) {
    size_t base = (size_t)(m0 + ty * 8 + i) * G4 + j0 + tx * 8;
    float4 o0 = make_float4(acc[i][0] + bv[0].x, acc[i][1] + bv[0].y,
                            acc[i][2] + bv[0].z, acc[i][3] + bv[0].w);
    float4 o1 = make_float4(acc[i][4] + bv[1].x, acc[i][5] + bv[1].y,
                            acc[i][6] + bv[1].z, acc[i][7] + bv[1].w);
    *reinterpret_cast<float4*>(&G[base]) = o0;
    *reinterpret_cast<float4*>(&G[base + 4]) = o1;
  }
}

// ---------------------------------------------------------------------------
// Phase 2: persistent recurrence. 64 WGs, 2 batch rows each, 512 threads.
// Thread t owns gate rows {t, t+512} for BOTH batch rows (weights loaded once,
// applied twice). Gate exchange via LDS; c held in a register per (b,j).
// GXMODE 0: read precomputed G.  GXMODE 1: compute x-contribution on the fly.
// ---------------------------------------------------------------------------
template <int GXMODE>
__global__ __launch_bounds__(512) void lstm_rec(
    const float* __restrict__ G,     // [T][B][1024] (mode 0)
    const float* __restrict__ x,     // [T][B][256]  (mode 1)
    const float* __restrict__ WT4h,  // [64][1024][4]
    const float* __restrict__ WT4i,  // [64][1024][4] (mode 1)
    const float* __restrict__ bih, const float* __restrict__ bhh,
    const float* __restrict__ h0, const float* __restrict__ c0,
    float* __restrict__ out) {
  __shared__ __align__(16) float h_lds[2][HSZ];
  __shared__ __align__(16) float x_lds[2][ISZ];
  __shared__ __align__(16) float g_lds[2][G4];

  const int wg = blockIdx.x;       // 0..63
  const int b0 = wg * 2;
  const int t  = threadIdx.x;      // 0..511
  const int r  = t;                // gate rows r and r+512
  const int ub = t >> 8;           // batch row this thread updates
  const int uj = t & 255;          // h/c column this thread updates

  h_lds[ub][uj] = h0[(b0 + ub) * HSZ + uj];
  float c = c0[(b0 + ub) * HSZ + uj];

  float bias0 = 0.f, bias1 = 0.f;
  if (GXMODE == 1) { bias0 = bih[r] + bhh[r]; bias1 = bih[r + 512] + bhh[r + 512]; }
  __syncthreads();

  // prefetch gx for step 0
  float p00 = 0.f, p01 = 0.f, p10 = 0.f, p11 = 0.f;
  if (GXMODE == 0) {
    const float* gx = G + (size_t)b0 * G4;
    p00 = gx[r]; p01 = gx[r + 512]; p10 = gx[G4 + r]; p11 = gx[G4 + r + 512];
  }

  for (int step = 0; step < T_STEPS; ++step) {
    float a00, a01, a10, a11;
    if (GXMODE == 0) {
      a00 = p00; a01 = p01; a10 = p10; a11 = p11;
      // prefetch next step's gx (hidden under the dot loop)
      int sn = step + 1 < T_STEPS ? step + 1 : step;
      const float* gx = G + (size_t)sn * BATCH * G4 + (size_t)b0 * G4;
      p00 = gx[r]; p01 = gx[r + 512]; p10 = gx[G4 + r]; p11 = gx[G4 + r + 512];
    } else {
      a00 = bias0; a01 = bias1; a10 = bias0; a11 = bias1;
      x_lds[ub][uj] = x[(size_t)step * BATCH * ISZ + (b0 + ub) * ISZ + uj];
      __syncthreads();
    }

    // recurrent GEMV: rows r, r+512 against h of both batch rows
    #pragma unroll 8
    for (int k4 = 0; k4 < 64; ++k4) {
      float4 w0 = *reinterpret_cast<const float4*>(&WT4h[k4 * 4096 + r * 4]);
      float4 w1 = *reinterpret_cast<const float4*>(&WT4h[k4 * 4096 + (r + 512) * 4]);
      float4 ha = *reinterpret_cast<const float4*>(&h_lds[0][k4 * 4]);
      float4 hb = *reinterpret_cast<const float4*>(&h_lds[1][k4 * 4]);
      a00 += w0.x * ha.x + w0.y * ha.y + w0.z * ha.z + w0.w * ha.w;
      a01 += w1.x * ha.x + w1.y * ha.y + w1.z * ha.z + w1.w * ha.w;
      a10 += w0.x * hb.x + w0.y * hb.y + w0.z * hb.z + w0.w * hb.w;
      a11 += w1.x * hb.x + w1.y * hb.y + w1.z * hb.z + w1.w * hb.w;
    }
    if (GXMODE == 1) {
      #pragma unroll 8
      for (int k4 = 0; k4 < 64; ++k4) {
        float4 w0 = *reinterpret_cast<const float4*>(&WT4i[k4 * 4096 + r * 4]);
        float4 w1 = *reinterpret_cast<const float4*>(&WT4i[k4 * 4096 + (r + 512) * 4]);
        float4 xa = *reinterpret_cast<const float4*>(&x_lds[0][k4 * 4]);
        float4 xb = *reinterpret_cast<const float4*>(&x_lds[1][k4 * 4]);
        a00 += w0.x * xa.x + w0.y * xa.y + w0.z * xa.z + w0.w * xa.w;
        a01 += w1.x * xa.x + w1.y * xa.y + w1.z * xa.z + w1.w * xa.w;
        a10 += w0.x * xb.x + w0.y * xb.y + w0.z * xb.z + w0.w * xb.w;
        a11 += w1.x * xb.x + w1.y * xb.y + w1.z * xb.z + w1.w * xb.w;
      }
    }

    g_lds[0][r] = a00; g_lds[0][r + 512] = a01;
    g_lds[1][r] = a10; g_lds[1][r + 512] = a11;
    __syncthreads();

    // gate nonlinearities + state update (PyTorch order i,f,g,o)
    float gi = g_lds[ub][uj];
    float gf = g_lds[ub][uj + 256];
    float gg = g_lds[ub][uj + 512];
    float go = g_lds[ub][uj + 768];
    gi = 1.f / (1.f + expf(-gi));
    gf = 1.f / (1.f + expf(-gf));
    go = 1.f / (1.f + expf(-go));
    gg = tanhf(gg);
    c = gf * c + gi * gg;
    float h = go * tanhf(c);
    h_lds[ub][uj] = h;
    out[(size_t)step * BATCH * HSZ + (b0 + ub) * HSZ + uj] = h;
    __syncthreads();
  }

  // finals: h_T then c_T
  out[(size_t)T_STEPS * BATCH * HSZ + (b0 + ub) * HSZ + uj] = h_lds[ub][uj];
  out[(size_t)T_STEPS * BATCH * HSZ + (size_t)BATCH * HSZ + (b0 + ub) * HSZ + uj] = c;
}

// ---------------------------------------------------------------------------
extern "C" void kernel_launch(void* const* d_in, const int* in_sizes, int n_in,
                              void* d_out, int out_size, void* d_ws, size_t ws_size,
                              hipStream_t stream) {
  const float* x   = (const float*)d_in[0];
  const float* h0  = (const float*)d_in[1];
  const float* c0  = (const float*)d_in[2];
  const float* Wih = (const float*)d_in[3];
  const float* Whh = (const float*)d_in[4];
  const float* bih = (const float*)d_in[5];
  const float* bhh = (const float*)d_in[6];
  float* out = (float*)d_out;

  char* ws = (char*)d_ws;
  float* WT4h = (float*)ws;                      // 1 MB
  float* WT4i = (float*)(ws + (1 << 20));        // 1 MB
  float* G    = (float*)(ws + (2 << 20));        // 268.4 MB if it fits

  const size_t need = (size_t)(2 << 20) + (size_t)T_STEPS * BATCH * G4 * 4;
  const bool big_ws = (ws_size >= need);

  prep_tables<<<1024, 256, 0, stream>>>(Whh, Wih, WT4h, WT4i);

  if (big_ws) {
    gemm_gates<<<dim3(8, 512), 256, 0, stream>>>(x, Wih, bih, bhh, G);
    lstm_rec<0><<<64, 512, 0, stream>>>(G, x, WT4h, WT4i, bih, bhh, h0, c0, out);
  } else {
    lstm_rec<1><<<64, 512, 0, stream>>>(nullptr, x, WT4h, WT4i, bih, bhh, h0, c0, out);
  }
}

// Round 7
// 5676.091 us; speedup vs baseline: 1.5900x; 1.5900x over previous
//
#include <hip/hip_runtime.h>
#include <hip/hip_bf16.h>
#include <math.h>

#define T_STEPS 512
#define BATCH   128
#define ISZ     256
#define HSZ     256
#define G4      1024   // 4*H
#define WIN     16     // gates_x window computed in-kernel
#define XPAD    4      // x_lds row pad (stride 260 floats)
#define KR      16     // k4 weight slices held in registers (128 VGPR)

// ---------------------------------------------------------------------------
// prep: transposed weight tables WT4[k4][row][c] = W[row][4*k4+c], so a wave
// reading lane-consecutive rows at fixed k4 issues coalesced float4 loads.
// ---------------------------------------------------------------------------
__global__ __launch_bounds__(256) void prep_tables(
    const float* __restrict__ W_hh, const float* __restrict__ W_ih,
    float* __restrict__ WT4h, float* __restrict__ WT4i) {
  int idx = blockIdx.x * 256 + threadIdx.x;   // 0 .. 262143
  int k4 = idx >> 12;          // 0..63
  int r  = (idx >> 2) & 1023;  // row
  int c  = idx & 3;
  WT4h[idx] = W_hh[r * 256 + k4 * 4 + c];
  WT4i[idx] = W_ih[r * 256 + k4 * 4 + c];
}

// ---------------------------------------------------------------------------
// Persistent fused LSTM: 128 WGs x 512 threads, one batch row per WG.
// Every WIN steps: stage x-window in LDS, compute gates_x for the window with
// a register-tiled GEMM (thread = 8 gate rows x 4 steps), store to LDS.
// Then WIN recurrent steps: thread t computes gate rows {t, t+512}.
// Streamed W_hh slices (k4 in [KR,64), from L2) are issued FIRST each step so
// their latency hides under the register-slice FMAs; the first KR slices live
// in registers for the whole kernel.
// ---------------------------------------------------------------------------
__global__ __launch_bounds__(512, 2) void lstm_fused(
    const float* __restrict__ x,     // [T][B][256]
    const float* __restrict__ WT4h,  // [64][1024][4]
    const float* __restrict__ WT4i,  // [64][1024][4]
    const float* __restrict__ bih, const float* __restrict__ bhh,
    const float* __restrict__ h0, const float* __restrict__ c0,
    float* __restrict__ out) {
  __shared__ __align__(16) float x_lds[WIN][HSZ + XPAD];  // 16.25 KB
  __shared__ __align__(16) float gx_lds[WIN][G4];         // 64 KB
  __shared__ __align__(16) float h_lds[HSZ];              // 1 KB
  __shared__ __align__(16) float g_lds[G4];               // 4 KB

  const int b = blockIdx.x;        // batch row
  const int t = threadIdx.x;       // 0..511
  const int r = t;                 // recurrent gate rows r, r+512
  const int rg = t >> 2;           // gemm row-group 0..127 (8 rows each)
  const int sg = t & 3;            // gemm step-group 0..3  (4 steps each)

  // per-thread bias for the 8 gemm gate rows (gates_x includes b_ih + b_hh)
  float bias_g[8];
  #pragma unroll
  for (int i = 0; i < 8; ++i) {
    int rr = rg * 8 + i;
    bias_g[i] = bih[rr] + bhh[rr];
  }

  // register-resident W_hh slices: k4 in [0, KR)
  float4 wr0[KR], wr1[KR];
  #pragma unroll
  for (int k = 0; k < KR; ++k) {
    wr0[k] = *reinterpret_cast<const float4*>(&WT4h[(size_t)k * 4096 + r * 4]);
    wr1[k] = *reinterpret_cast<const float4*>(&WT4h[(size_t)k * 4096 + (r + 512) * 4]);
  }

  if (t < HSZ) h_lds[t] = h0[b * HSZ + t];
  float c = (t < HSZ) ? c0[b * HSZ + t] : 0.f;
  __syncthreads();

  for (int w = 0; w < T_STEPS / WIN; ++w) {
    const int s0 = w * WIN;

    // ---- stage x window: WIN*256 floats = 1024 float4s, 2 per thread ----
    #pragma unroll
    for (int j = 0; j < 2; ++j) {
      int f = t + j * 512;               // 0..1023
      int s = f >> 6, kq = f & 63;       // 64 float4s per step row
      float4 v = reinterpret_cast<const float4*>(x)[((size_t)(s0 + s) * BATCH + b) * 64 + kq];
      *reinterpret_cast<float4*>(&x_lds[s][kq * 4]) = v;
    }
    __syncthreads();

    // ---- windowed gates_x GEMM: acc[8 rows][4 steps] ----
    float acc[8][4];
    #pragma unroll
    for (int i = 0; i < 8; ++i)
      #pragma unroll
      for (int ss = 0; ss < 4; ++ss) acc[i][ss] = bias_g[i];

    #pragma unroll 4
    for (int k4 = 0; k4 < 64; ++k4) {
      float4 xv[4];
      #pragma unroll
      for (int ss = 0; ss < 4; ++ss)
        xv[ss] = *reinterpret_cast<const float4*>(&x_lds[sg * 4 + ss][k4 * 4]);
      #pragma unroll
      for (int i = 0; i < 8; ++i) {
        float4 wv = *reinterpret_cast<const float4*>(&WT4i[(size_t)k4 * 4096 + (rg * 8 + i) * 4]);
        #pragma unroll
        for (int ss = 0; ss < 4; ++ss)
          acc[i][ss] += wv.x * xv[ss].x + wv.y * xv[ss].y + wv.z * xv[ss].z + wv.w * xv[ss].w;
      }
    }
    #pragma unroll
    for (int i = 0; i < 8; ++i)
      #pragma unroll
      for (int ss = 0; ss < 4; ++ss)
        gx_lds[sg * 4 + ss][rg * 8 + i] = acc[i][ss];
    __syncthreads();

    // ---- WIN recurrent steps ----
    for (int s = 0; s < WIN; ++s) {
      float a0 = gx_lds[s][r];
      float a1 = gx_lds[s][r + 512];

      // streamed slices FIRST (k4 in [KR,64)): loads issue immediately after
      // the barrier; their L2 latency hides under the register-slice FMAs
      // below. unroll 8 -> up to 16 float4s in flight.
      float sa0 = 0.f, sa1 = 0.f;
      #pragma unroll 8
      for (int k4 = KR; k4 < 64; ++k4) {
        float4 w0 = *reinterpret_cast<const float4*>(&WT4h[(size_t)k4 * 4096 + r * 4]);
        float4 w1 = *reinterpret_cast<const float4*>(&WT4h[(size_t)k4 * 4096 + (r + 512) * 4]);
        float4 hv = *reinterpret_cast<const float4*>(&h_lds[k4 * 4]);
        sa0 += w0.x * hv.x + w0.y * hv.y + w0.z * hv.z + w0.w * hv.w;
        sa1 += w1.x * hv.x + w1.y * hv.y + w1.z * hv.z + w1.w * hv.w;
      }
      // register-resident slices (k4 in [0, KR)) — pure VALU, no loads
      #pragma unroll
      for (int k = 0; k < KR; ++k) {
        float4 hv = *reinterpret_cast<const float4*>(&h_lds[k * 4]);
        a0 += wr0[k].x * hv.x + wr0[k].y * hv.y + wr0[k].z * hv.z + wr0[k].w * hv.w;
        a1 += wr1[k].x * hv.x + wr1[k].y * hv.y + wr1[k].z * hv.z + wr1[k].w * hv.w;
      }
      a0 += sa0;
      a1 += sa1;
      g_lds[r] = a0;
      g_lds[r + 512] = a1;
      __syncthreads();

      if (t < HSZ) {
        float gi = g_lds[t];
        float gf = g_lds[t + 256];
        float gg = g_lds[t + 512];
        float go = g_lds[t + 768];
        gi = 1.f / (1.f + expf(-gi));
        gf = 1.f / (1.f + expf(-gf));
        go = 1.f / (1.f + expf(-go));
        gg = tanhf(gg);
        c = gf * c + gi * gg;
        float h = go * tanhf(c);
        h_lds[t] = h;
        out[(size_t)(s0 + s) * BATCH * HSZ + b * HSZ + t] = h;
      }
      __syncthreads();   // protects h_lds (next step) and gx_lds/x_lds (next window)
    }
  }

  // finals: h_T then c_T
  if (t < HSZ) {
    out[(size_t)T_STEPS * BATCH * HSZ + b * HSZ + t] = h_lds[t];
    out[(size_t)T_STEPS * BATCH * HSZ + (size_t)BATCH * HSZ + b * HSZ + t] = c;
  }
}

// ---------------------------------------------------------------------------
extern "C" void kernel_launch(void* const* d_in, const int* in_sizes, int n_in,
                              void* d_out, int out_size, void* d_ws, size_t ws_size,
                              hipStream_t stream) {
  const float* x   = (const float*)d_in[0];
  const float* h0  = (const float*)d_in[1];
  const float* c0  = (const float*)d_in[2];
  const float* Wih = (const float*)d_in[3];
  const float* Whh = (const float*)d_in[4];
  const float* bih = (const float*)d_in[5];
  const float* bhh = (const float*)d_in[6];
  float* out = (float*)d_out;

  char* ws = (char*)d_ws;
  float* WT4h = (float*)ws;                 // 1 MB
  float* WT4i = (float*)(ws + (1 << 20));   // 1 MB

  prep_tables<<<1024, 256, 0, stream>>>(Whh, Wih, WT4h, WT4i);
  lstm_fused<<<BATCH, 512, 0, stream>>>(x, WT4h, WT4i, bih, bhh, h0, c0, out);
}